// Round 4
// baseline (1296.289 us; speedup 1.0000x reference)
//
#include <hip/hip_runtime.h>
#include <hip/hip_bf16.h>
#include <math.h>

typedef unsigned short u16;
typedef __attribute__((ext_vector_type(4))) float f32x4;
typedef __attribute__((ext_vector_type(8))) short s16x8;

__device__ __forceinline__ float b2f(u16 u){
  union { unsigned u; float f; } v; v.u = ((unsigned)u) << 16; return v.f;
}
__device__ __forceinline__ u16 f2b(float f){
  union { float f; unsigned u; } v; v.f = f;
  unsigned r = v.u + 0x7fffu + ((v.u >> 16) & 1u);
  return (u16)(r >> 16);
}

__global__ void zero_k(int* __restrict__ p, int n){
  int i = blockIdx.x*256 + threadIdx.x;
  if(i < n) p[i] = 0;
}

// ---------- prep: W fp32 [K,256] row-major -> bf16 WT [256,K] ----------
__global__ void transpose_k(const float* __restrict__ W, u16* __restrict__ WT, int K){
  int idx = blockIdx.x*256 + threadIdx.x;
  if(idx < K*256){ int k = idx >> 8, n = idx & 255; WT[n*K + k] = f2b(W[idx]); }
}

// folded: WT'[n=32h+f][k] = sum_d Wk[k][32h+d] * A[h][d][f]  (fp32 math, bf16 out)
__global__ void fold_w(const float* __restrict__ Wk, const float* __restrict__ A, u16* __restrict__ WT){
  int idx = blockIdx.x*256 + threadIdx.x;
  int n = idx >> 8, k = idx & 255;
  int h = n >> 5, f = n & 31;
  float s = 0.f;
  #pragma unroll 8
  for(int d = 0; d < 32; d++)
    s += Wk[k*256 + h*32 + d] * A[h*1024 + d*32 + f];
  WT[n*256 + k] = f2b(s);
}

__global__ void fold_b(const float* __restrict__ bk, const float* __restrict__ A, float* __restrict__ bo){
  int n = threadIdx.x;
  int h = n >> 5, f = n & 31;
  float s = 0.f;
  for(int d = 0; d < 32; d++)
    s += bk[h*32 + d] * A[h*1024 + d*32 + f];
  bo[n] = s;
}

// ---------- GEMM: C[M,256] = A[M,K] @ B + bias ; B transposed bf16 BT[256,K] ----------
// AFP32: A operand is fp32 (converted to bf16 during LDS staging). OUTF32: C written fp32.
template<int AFP32, int OUTF32>
__global__ __launch_bounds__(256) void gemm_k(
    const void* __restrict__ A, const u16* __restrict__ BT,
    const float* __restrict__ bias, void* __restrict__ Cout,
    int M, int K)
{
  __shared__ short As[64*40];
  __shared__ short Bs[64*40];
  const int t = threadIdx.x;
  const int m0 = blockIdx.x << 6;
  const int n0 = blockIdx.y << 6;
  const int wave = t >> 6, lane = t & 63;
  const int lrow = lane & 15, lq = lane >> 4;
  const int r = t >> 2, seg = t & 3;
  const int gm = m0 + r;
  f32x4 acc[4] = {{0.f,0.f,0.f,0.f},{0.f,0.f,0.f,0.f},{0.f,0.f,0.f,0.f},{0.f,0.f,0.f,0.f}};
  for(int k0 = 0; k0 < K; k0 += 32){
    s16x8 av = {0,0,0,0,0,0,0,0};
    if(AFP32){
      if(gm < M){
        const float* Af = (const float*)A + (size_t)gm*K + k0 + seg*8;
        float4 f0 = *(const float4*)Af;
        float4 f1 = *(const float4*)(Af + 4);
        av[0]=(short)f2b(f0.x); av[1]=(short)f2b(f0.y); av[2]=(short)f2b(f0.z); av[3]=(short)f2b(f0.w);
        av[4]=(short)f2b(f1.x); av[5]=(short)f2b(f1.y); av[6]=(short)f2b(f1.z); av[7]=(short)f2b(f1.w);
      }
    } else {
      if(gm < M) av = *(const s16x8*)((const u16*)A + (size_t)gm*K + k0 + seg*8);
    }
    s16x8 bv = *(const s16x8*)(BT + (size_t)(n0 + r)*K + k0 + seg*8);
    *(s16x8*)&As[r*40 + seg*8] = av;
    *(s16x8*)&Bs[r*40 + seg*8] = bv;
    __syncthreads();
    s16x8 a = *(const s16x8*)&As[(wave*16 + lrow)*40 + lq*8];
    #pragma unroll
    for(int nt = 0; nt < 4; nt++){
      s16x8 b = *(const s16x8*)&Bs[(nt*16 + lrow)*40 + lq*8];
      acc[nt] = __builtin_amdgcn_mfma_f32_16x16x32_bf16(a, b, acc[nt], 0, 0, 0);
    }
    __syncthreads();
  }
  const int row_base = m0 + wave*16 + lq*4;
  #pragma unroll
  for(int nt = 0; nt < 4; nt++){
    const int col = n0 + nt*16 + lrow;
    const float bcol = bias[col];
    #pragma unroll
    for(int i = 0; i < 4; i++){
      const int row = row_base + i;
      if(row < M){
        float v = acc[nt][i] + bcol;
        if(OUTF32) ((float*)Cout)[(size_t)row*256 + col] = v;
        else       ((u16*)Cout)[(size_t)row*256 + col] = f2b(v);
      }
    }
  }
}

// ---------- CSR build ----------
__global__ void edge_count(const int* __restrict__ dst, int E, int* __restrict__ cnt){
  int e = blockIdx.x*256 + threadIdx.x;
  if(e < E) atomicAdd(&cnt[dst[e]], 1);
}
__global__ void edge_alloc(const int* __restrict__ cnt, int n, int* __restrict__ rs, int* __restrict__ tot){
  int i = blockIdx.x*256 + threadIdx.x;
  if(i < n) rs[i] = atomicAdd(tot, cnt[i]);
}
__global__ void edge_fill(const int* __restrict__ src, const int* __restrict__ dst, int E,
                          const int* __restrict__ rs, int* __restrict__ cur, int* __restrict__ col){
  int e = blockIdx.x*256 + threadIdx.x;
  if(e < E){
    int d = dst[e];
    int p = rs[d] + atomicAdd(&cur[d], 1);
    col[p] = src[e];
  }
}

// ---------- message pass + gelu, IN-PLACE over fp32 Q row; online softmax ----------
template<int NREL>
__global__ __launch_bounds__(256) void message_gelu_k(
    const u16* __restrict__ K1, const u16* __restrict__ V1, const float* __restrict__ p1,
    const int* __restrict__ rs1, const int* __restrict__ cnt1, const int* __restrict__ col1, int nsrc1,
    const u16* __restrict__ K2, const u16* __restrict__ V2, const float* __restrict__ p2,
    const int* __restrict__ rs2, const int* __restrict__ cnt2, const int* __restrict__ col2, int nsrc2,
    float* __restrict__ Qio, int n_dst)
{
  int node = (blockIdx.x << 2) + (threadIdx.x >> 6);
  if(node >= n_dst) return;
  int lane = threadIdx.x & 63;
  int base = node*256 + (lane << 2);
  float4 qv = *(const float4*)(Qio + base);
  float q0=qv.x, q1=qv.y, q2=qv.z, q3=qv.w;
  float o0=0.f, o1=0.f, o2=0.f, o3=0.f;
  #pragma unroll
  for(int rel = 0; rel < NREL; rel++){
    const u16* Kr = rel ? K2 : K1;
    const u16* Vr = rel ? V2 : V1;
    const float* pr = rel ? p2 : p1;
    const int* rs = rel ? rs2 : rs1;
    const int* cn = rel ? cnt2 : cnt1;
    const int* cl = rel ? col2 : col1;
    const unsigned ns = (unsigned)(rel ? nsrc2 : nsrc1);
    float ps = pr[lane >> 3] * 0.17677669529663687f;   // p[h]/sqrt(32)
    float a0=0.f,a1=0.f,a2=0.f,a3=0.f,ss=0.f,mx=-1e30f;
    int r0 = rs[node], deg = cn[node];
    for(int i = 0; i < deg; i++){
      int s = cl[r0 + i];
      if((unsigned)s >= ns) continue;          // guard (no-op if CSR correct)
      int kb = s*256 + (lane << 2);
      ushort4 kv = *(const ushort4*)(Kr + kb);
      float d = q0*b2f(kv.x) + q1*b2f(kv.y) + q2*b2f(kv.z) + q3*b2f(kv.w);
      d += __shfl_xor(d, 1);
      d += __shfl_xor(d, 2);
      d += __shfl_xor(d, 4);
      float l = d * ps;
      if(l > mx){                              // online max-subtraction (exact)
        float c = __expf(mx - l);
        ss *= c; a0 *= c; a1 *= c; a2 *= c; a3 *= c;
        mx = l;
      }
      float w = __expf(l - mx);                // <= 1
      ss += w;
      ushort4 vv = *(const ushort4*)(Vr + kb);
      a0 += w*b2f(vv.x); a1 += w*b2f(vv.y); a2 += w*b2f(vv.z); a3 += w*b2f(vv.w);
    }
    float inv = 1.f/(ss + 1e-16f);
    o0 += a0*inv; o1 += a1*inv; o2 += a2*inv; o3 += a3*inv;
  }
  const float c = 0.70710678118654752f;
  float4 ov;
  ov.x = 0.5f*o0*(1.f + erff(o0*c));
  ov.y = 0.5f*o1*(1.f + erff(o1*c));
  ov.z = 0.5f*o2*(1.f + erff(o2*c));
  ov.w = 0.5f*o3*(1.f + erff(o3*c));
  *(float4*)(Qio + base) = ov;
}

// ---------- final GEMM, IN-PLACE over d_out: h=G@WTa+ba; beta-mix with X; PReLU ----------
__global__ __launch_bounds__(256) void epilogue_k(
    const float* __restrict__ G, const u16* __restrict__ WTa,
    const float* __restrict__ ba, const u16* __restrict__ X,
    const float* __restrict__ skip, const float* __restrict__ prelu,
    float* __restrict__ OUT, int M)
{
  __shared__ short As[64*40];
  __shared__ short Bs[256*40];
  const int t = threadIdx.x;
  const int m0 = blockIdx.x << 6;
  const int wave = t >> 6, lane = t & 63;
  const int lrow = lane & 15, lq = lane >> 4;
  const int r = t >> 2, seg = t & 3;
  const int gm = m0 + r;
  f32x4 acc[16];
  #pragma unroll
  for(int i = 0; i < 16; i++) acc[i] = (f32x4){0.f,0.f,0.f,0.f};
  for(int k0 = 0; k0 < 256; k0 += 32){
    s16x8 av = {0,0,0,0,0,0,0,0};
    if(gm < M){
      const float* Gf = G + (size_t)gm*256 + k0 + seg*8;
      float4 f0 = *(const float4*)Gf;
      float4 f1 = *(const float4*)(Gf + 4);
      av[0]=(short)f2b(f0.x); av[1]=(short)f2b(f0.y); av[2]=(short)f2b(f0.z); av[3]=(short)f2b(f0.w);
      av[4]=(short)f2b(f1.x); av[5]=(short)f2b(f1.y); av[6]=(short)f2b(f1.z); av[7]=(short)f2b(f1.w);
    }
    *(s16x8*)&As[r*40 + seg*8] = av;
    #pragma unroll
    for(int s = 0; s < 4; s++)
      *(s16x8*)&Bs[t*40 + s*8] = *(const s16x8*)(WTa + (size_t)t*256 + k0 + s*8);
    __syncthreads();
    s16x8 a = *(const s16x8*)&As[(wave*16 + lrow)*40 + lq*8];
    #pragma unroll
    for(int nt = 0; nt < 16; nt++){
      s16x8 b = *(const s16x8*)&Bs[(nt*16 + lrow)*40 + lq*8];
      acc[nt] = __builtin_amdgcn_mfma_f32_16x16x32_bf16(a, b, acc[nt], 0, 0, 0);
    }
    __syncthreads();
  }
  const float beta = 1.f/(1.f + __expf(-skip[0]));
  const int row_base = m0 + wave*16 + lq*4;
  #pragma unroll
  for(int nt = 0; nt < 16; nt++){
    const int col = nt*16 + lrow;
    const float bcol = ba[col];
    const float pw = prelu[col];
    #pragma unroll
    for(int i = 0; i < 4; i++){
      const int row = row_base + i;
      if(row < M){
        float v = acc[nt][i] + bcol;
        float xv = b2f(X[(size_t)row*256 + col]);
        v = beta*v + (1.f - beta)*xv;
        v = v > 0.f ? v : pw*v;
        OUT[(size_t)row*256 + col] = v;
      }
    }
  }
}

extern "C" void kernel_launch(void* const* d_in, const int* in_sizes, int n_in,
                              void* d_out, int out_size, void* d_ws, size_t ws_size,
                              hipStream_t stream)
{
  (void)n_in; (void)out_size; (void)ws_size;
  #define IN_F32(i) ((const float*)d_in[i])
  #define IN_I32(i) ((const int*)d_in[i])
  const int NG = in_sizes[0] / 128;
  const int ND = in_sizes[1] / 128;
  const int E  = in_sizes[34];

  char* p = (char*)d_ws;
  auto carve = [&](size_t bytes) -> void* {
    void* q = (void*)p; p += (bytes + 255) & ~(size_t)255; return q;
  };
  u16* XG   = (u16*)carve((size_t)NG*256*2);   // bf16 xproj g
  u16* XD   = (u16*)carve((size_t)ND*256*2);   // bf16 xproj d
  u16* bufA = (u16*)carve((size_t)NG*256*2);   // g2d K, then g2g K (bf16)
  u16* bufB = (u16*)carve((size_t)NG*256*2);   // g2d V, then g2g V (bf16)
  u16* KB   = (u16*)carve((size_t)ND*256*2);
  u16* VB   = (u16*)carve((size_t)ND*256*2);
  u16* WTinG = (u16*)carve(256*128*2);
  u16* WTinD = (u16*)carve(256*128*2);
  u16* WTqG  = (u16*)carve(256*256*2);
  u16* WTqD  = (u16*)carve(256*256*2);
  u16* WTaG  = (u16*)carve(256*256*2);
  u16* WTaD  = (u16*)carve(256*256*2);
  u16* WF[6]; for(int i=0;i<6;i++) WF[i] = (u16*)carve(256*256*2);
  float* FB[6]; for(int i=0;i<6;i++) FB[i] = (float*)carve(256*4);
  int* cntA = (int*)carve((size_t)NG*4);
  int* rsA  = (int*)carve((size_t)NG*4);
  int* curA = (int*)carve((size_t)NG*4);
  int* colA = (int*)carve((size_t)E*4);
  int* cntB = (int*)carve((size_t)NG*4);
  int* rsB  = (int*)carve((size_t)NG*4);
  int* curB = (int*)carve((size_t)NG*4);
  int* colB = (int*)carve((size_t)E*4);
  int* totA = (int*)carve(256);
  int* totB = (int*)carve(256);

  float* QGio = (float*)d_out;                     // fp32 [NG,256]
  float* QDio = (float*)d_out + (size_t)NG*256;    // fp32 [ND,256]

  transpose_k<<<128, 256, 0, stream>>>(IN_F32(2),  WTinG, 128);
  transpose_k<<<128, 256, 0, stream>>>(IN_F32(13), WTinD, 128);
  transpose_k<<<256, 256, 0, stream>>>(IN_F32(6),  WTqG, 256);
  transpose_k<<<256, 256, 0, stream>>>(IN_F32(17), WTqD, 256);
  transpose_k<<<256, 256, 0, stream>>>(IN_F32(10), WTaG, 256);
  transpose_k<<<256, 256, 0, stream>>>(IN_F32(21), WTaD, 256);
  fold_w<<<256, 256, 0, stream>>>(IN_F32(4),  IN_F32(24), WF[0]);  // Wk_g * a_g2d
  fold_w<<<256, 256, 0, stream>>>(IN_F32(8),  IN_F32(25), WF[1]);  // Wv_g * m_g2d
  fold_w<<<256, 256, 0, stream>>>(IN_F32(15), IN_F32(27), WF[2]);  // Wk_d * a_d2g
  fold_w<<<256, 256, 0, stream>>>(IN_F32(19), IN_F32(28), WF[3]);  // Wv_d * m_d2g
  fold_w<<<256, 256, 0, stream>>>(IN_F32(4),  IN_F32(30), WF[4]);  // Wk_g * a_g2g
  fold_w<<<256, 256, 0, stream>>>(IN_F32(8),  IN_F32(31), WF[5]);  // Wv_g * m_g2g
  fold_b<<<1, 256, 0, stream>>>(IN_F32(5),  IN_F32(24), FB[0]);
  fold_b<<<1, 256, 0, stream>>>(IN_F32(9),  IN_F32(25), FB[1]);
  fold_b<<<1, 256, 0, stream>>>(IN_F32(16), IN_F32(27), FB[2]);
  fold_b<<<1, 256, 0, stream>>>(IN_F32(20), IN_F32(28), FB[3]);
  fold_b<<<1, 256, 0, stream>>>(IN_F32(5),  IN_F32(30), FB[4]);
  fold_b<<<1, 256, 0, stream>>>(IN_F32(9),  IN_F32(31), FB[5]);

  dim3 gG((unsigned)((NG + 63) / 64), 4);
  dim3 gD((unsigned)((ND + 63) / 64), 4);
  const int eb = (E + 255) / 256;
  auto build_csr = [&](const int* src, const int* dst, int ndst,
                       int* cnt, int* rs, int* cur, int* tot, int* col){
    int nb = (ndst + 255) / 256;
    zero_k<<<nb, 256, 0, stream>>>(cnt, ndst);
    zero_k<<<nb, 256, 0, stream>>>(cur, ndst);
    zero_k<<<1, 256, 0, stream>>>(tot, 1);
    edge_count<<<eb, 256, 0, stream>>>(dst, E, cnt);
    edge_alloc<<<nb, 256, 0, stream>>>(cnt, ndst, rs, tot);
    edge_fill<<<eb, 256, 0, stream>>>(src, dst, E, rs, cur, col);
  };

  // input projections: A fp32, C bf16
  gemm_k<1,0><<<gG, 256, 0, stream>>>(d_in[0], WTinG, IN_F32(3),  XG, NG, 128);
  gemm_k<1,0><<<gD, 256, 0, stream>>>(d_in[1], WTinD, IN_F32(14), XD, ND, 128);

  // relation g2d (src=g, dst=d): Q fp32 into d_out, K/V bf16
  gemm_k<0,1><<<gD, 256, 0, stream>>>(XD, WTqD,  IN_F32(18), QDio, ND, 256);
  gemm_k<0,0><<<gG, 256, 0, stream>>>(XG, WF[0], FB[0], bufA, NG, 256);
  gemm_k<0,0><<<gG, 256, 0, stream>>>(XG, WF[1], FB[1], bufB, NG, 256);
  build_csr(IN_I32(34), IN_I32(35), ND, cntA, rsA, curA, totA, colA);
  message_gelu_k<1><<<(ND + 3) / 4, 256, 0, stream>>>(
      bufA, bufB, IN_F32(26), rsA, cntA, colA, NG,
      nullptr, nullptr, nullptr, nullptr, nullptr, nullptr, 0,
      QDio, ND);

  // relations d2g + g2g (dst=g)
  gemm_k<0,1><<<gG, 256, 0, stream>>>(XG, WTqG,  IN_F32(7), QGio, NG, 256);
  gemm_k<0,0><<<gD, 256, 0, stream>>>(XD, WF[2], FB[2], KB, ND, 256);
  gemm_k<0,0><<<gD, 256, 0, stream>>>(XD, WF[3], FB[3], VB, ND, 256);
  gemm_k<0,0><<<gG, 256, 0, stream>>>(XG, WF[4], FB[4], bufA, NG, 256);
  gemm_k<0,0><<<gG, 256, 0, stream>>>(XG, WF[5], FB[5], bufB, NG, 256);
  build_csr(IN_I32(36), IN_I32(37), NG, cntA, rsA, curA, totA, colA);  // d2g
  build_csr(IN_I32(38), IN_I32(39), NG, cntB, rsB, curB, totB, colB);  // g2g
  message_gelu_k<2><<<(NG + 3) / 4, 256, 0, stream>>>(
      KB, VB, IN_F32(29), rsA, cntA, colA, ND,
      bufA, bufB, IN_F32(32), rsB, cntB, colB, NG,
      QGio, NG);

  // final per-type GEMM + skip-mix + PReLU, in place over d_out (fp32)
  epilogue_k<<<(NG + 63) / 64, 256, 0, stream>>>(
      QGio, WTaG, IN_F32(11), XG, IN_F32(12), IN_F32(33), QGio, NG);
  epilogue_k<<<(ND + 63) / 64, 256, 0, stream>>>(
      QDio, WTaD, IN_F32(22), XD, IN_F32(23), IN_F32(33), QDio, ND);
  #undef IN_F32
  #undef IN_I32
}

// Round 5
// 1273.958 us; speedup vs baseline: 1.0175x; 1.0175x over previous
//
#include <hip/hip_runtime.h>
#include <hip/hip_bf16.h>
#include <math.h>

typedef unsigned short u16;
typedef __attribute__((ext_vector_type(4))) float f32x4;
typedef __attribute__((ext_vector_type(8))) short s16x8;

__device__ __forceinline__ float b2f(u16 u){
  union { unsigned u; float f; } v; v.u = ((unsigned)u) << 16; return v.f;
}
__device__ __forceinline__ u16 f2b(float f){
  union { float f; unsigned u; } v; v.f = f;
  unsigned r = v.u + 0x7fffu + ((v.u >> 16) & 1u);
  return (u16)(r >> 16);
}

// async global->LDS, 16B per lane; LDS dest = wave-uniform base + lane*16
__device__ __forceinline__ void gload_lds(const u16* g, u16* l){
  __builtin_amdgcn_global_load_lds(
      (const __attribute__((address_space(1))) unsigned*)g,
      (__attribute__((address_space(3))) unsigned*)l, 16, 0, 0);
}

__global__ void zero_k(int* __restrict__ p, int n){
  int i = blockIdx.x*256 + threadIdx.x;
  if(i < n) p[i] = 0;
}

// ---------- batched prep kernels ----------
struct T6 { const float* W[6]; u16* O[6]; int K[6]; };
__global__ void transpose6(T6 a){
  int r = blockIdx.y;
  int idx = blockIdx.x*256 + threadIdx.x;
  int K = a.K[r];
  if(idx < K*256){ int k = idx >> 8, n = idx & 255; a.O[r][n*K + k] = f2b(a.W[r][idx]); }
}

struct F6 { const float* Wk[6]; const float* A[6]; u16* O[6]; };
__global__ void foldw6(F6 fa){
  int r = blockIdx.y;
  int idx = blockIdx.x*256 + threadIdx.x;
  int n = idx >> 8, k = idx & 255;
  int h = n >> 5, f = n & 31;
  const float* Wk = fa.Wk[r]; const float* A = fa.A[r];
  float s = 0.f;
  #pragma unroll 8
  for(int d = 0; d < 32; d++)
    s += Wk[k*256 + h*32 + d] * A[h*1024 + d*32 + f];
  fa.O[r][n*256 + k] = f2b(s);
}

struct Fb6 { const float* bk[6]; const float* A[6]; float* O[6]; };
__global__ void foldb6(Fb6 fa){
  int r = blockIdx.x;
  int n = threadIdx.x;
  int h = n >> 5, f = n & 31;
  float s = 0.f;
  for(int d = 0; d < 32; d++)
    s += fa.bk[r][h*32 + d] * fa.A[r][h*1024 + d*32 + f];
  fa.O[r][n] = s;
}

// ---------- batched CSR build (3 relations) ----------
struct CSR3 {
  const int* src[3]; const int* dst[3]; int n[3];
  int* cnt[3]; int* rs[3]; int* cur[3]; int* col[3]; int* tot[3];
};
__global__ void count3(CSR3 c, int E){
  int r = blockIdx.y;
  int e = blockIdx.x*256 + threadIdx.x;
  if(e < E) atomicAdd(&c.cnt[r][c.dst[r][e]], 1);
}
__global__ void alloc3(CSR3 c){
  int r = blockIdx.y;
  int i = blockIdx.x*256 + threadIdx.x;
  if(i < c.n[r]) c.rs[r][i] = atomicAdd(c.tot[r], c.cnt[r][i]);
}
__global__ void fill3(CSR3 c, int E){
  int r = blockIdx.y;
  int e = blockIdx.x*256 + threadIdx.x;
  if(e < E){
    int d = c.dst[r][e];
    int p = c.rs[r][d] + atomicAdd(&c.cur[r][d], 1);
    c.col[r][p] = c.src[r][e];
  }
}

// ---------- GEMM: C[M,256] = A[M,K] @ B + bias ; BT[N,K] bf16 ----------
// AF: A operand fp32 (converted during explicit LDS staging); else bf16 via global_load_lds.
// EPI 0: C bf16 + bias. EPI 1: C fp32 + bias. EPI 2: in-place epilogue (64x256 block:
//   one block owns the full 256-col row strip -> in-place over d_out is race-free):
//   v = acc+ba; v = beta*v + (1-beta)*X; PReLU; fp32 out.
// LDS: row-major [rows x 32], 16B segs XOR-swizzled by (row&3) -> 4-way max conflict.
template<int AF, int EPI>
__global__ __launch_bounds__(256) void gemm128(
    const void* __restrict__ Ap, const u16* __restrict__ BT,
    const float* __restrict__ bias, void* __restrict__ Cout,
    int M, int K,
    const u16* __restrict__ X, const float* __restrict__ skip,
    const float* __restrict__ prelu)
{
  constexpr int BM = (EPI == 2) ? 64 : 128;
  constexpr int BN = (EPI == 2) ? 256 : 128;
  __shared__ u16 As[BM*32];
  __shared__ u16 Bs[BN*32];
  const int t = threadIdx.x;
  const int m0 = blockIdx.x * BM;
  const int n0 = blockIdx.y * BN;
  const int w = t >> 6, lane = t & 63;
  const int wm = (EPI==2) ? 0 : ((w >> 1) << 6);
  const int wn = (EPI==2) ? (w << 6) : ((w & 1) << 6);
  const int lr = lane & 15, lq = lane >> 4;
  const int jr = lane >> 2;          // staging: row-in-16
  const int sp = lane & 3;           // staging: physical 16B slot
  f32x4 acc[4][4];
  #pragma unroll
  for(int i=0;i<4;i++)
    #pragma unroll
    for(int j=0;j<4;j++) acc[i][j] = (f32x4){0.f,0.f,0.f,0.f};

  for(int k0 = 0; k0 < K; k0 += 32){
    if(AF){
      const float* Af = (const float*)Ap;
      constexpr int NS = BM*4;
      #pragma unroll
      for(int j = 0; j < NS/256; j++){
        int s = t + j*256;
        int rr = s >> 2, p2 = s & 3;
        int sl = p2 ^ (rr & 3);
        int gm = m0 + rr; if(gm > M-1) gm = M-1;
        const float* g = Af + (size_t)gm*K + k0 + sl*8;
        float4 f0 = *(const float4*)g;
        float4 f1 = *(const float4*)(g + 4);
        s16x8 v;
        v[0]=(short)f2b(f0.x); v[1]=(short)f2b(f0.y); v[2]=(short)f2b(f0.z); v[3]=(short)f2b(f0.w);
        v[4]=(short)f2b(f1.x); v[5]=(short)f2b(f1.y); v[6]=(short)f2b(f1.z); v[7]=(short)f2b(f1.w);
        *(s16x8*)&As[rr*32 + p2*8] = v;
      }
    } else {
      const u16* Ab = (const u16*)Ap;
      constexpr int RA = BM/4;
      #pragma unroll
      for(int i = 0; i < RA/16; i++){
        int rr = w*RA + i*16 + jr;
        int sl = sp ^ (rr & 3);
        int gm = m0 + rr; if(gm > M-1) gm = M-1;
        gload_lds(Ab + (size_t)gm*K + k0 + sl*8, &As[(w*RA + i*16)*32]);
      }
    }
    {
      constexpr int RB = BN/4;
      #pragma unroll
      for(int i = 0; i < RB/16; i++){
        int rr = w*RB + i*16 + jr;
        int sl = sp ^ (rr & 3);
        gload_lds(BT + (size_t)(n0 + rr)*K + k0 + sl*8, &Bs[(w*RB + i*16)*32]);
      }
    }
    __syncthreads();
    s16x8 a[4], b[4];
    #pragma unroll
    for(int mt=0; mt<4; mt++)
      a[mt] = *(const s16x8*)&As[(wm + mt*16 + lr)*32 + ((lq ^ (lr&3)) << 3)];
    #pragma unroll
    for(int nt=0; nt<4; nt++)
      b[nt] = *(const s16x8*)&Bs[(wn + nt*16 + lr)*32 + ((lq ^ (lr&3)) << 3)];
    #pragma unroll
    for(int mt=0; mt<4; mt++)
      #pragma unroll
      for(int nt=0; nt<4; nt++)
        acc[mt][nt] = __builtin_amdgcn_mfma_f32_16x16x32_bf16(a[mt], b[nt], acc[mt][nt], 0, 0, 0);
    __syncthreads();
  }

  float beta = 0.f;
  if(EPI == 2) beta = 1.f/(1.f + __expf(-skip[0]));
  #pragma unroll
  for(int nt=0; nt<4; nt++){
    const int col = n0 + wn + nt*16 + lr;
    const float bcol = bias[col];
    float pw = 0.f;
    if(EPI == 2) pw = prelu[col];
    #pragma unroll
    for(int mt=0; mt<4; mt++){
      #pragma unroll
      for(int i=0;i<4;i++){
        int row = m0 + wm + mt*16 + lq*4 + i;
        if(row < M){
          float v = acc[mt][nt][i] + bcol;
          if(EPI == 0) ((u16*)Cout)[(size_t)row*256 + col] = f2b(v);
          else if(EPI == 1) ((float*)Cout)[(size_t)row*256 + col] = v;
          else {
            float xv = b2f(X[(size_t)row*256 + col]);
            v = beta*v + (1.f - beta)*xv;
            v = v > 0.f ? v : pw*v;
            ((float*)Cout)[(size_t)row*256 + col] = v;
          }
        }
      }
    }
  }
}

// ---------- message pass + gelu, IN-PLACE over fp32 Q row; online softmax ----------
template<int NREL>
__global__ __launch_bounds__(256) void message_gelu_k(
    const u16* __restrict__ K1, const u16* __restrict__ V1, const float* __restrict__ p1,
    const int* __restrict__ rs1, const int* __restrict__ cnt1, const int* __restrict__ col1, int nsrc1,
    const u16* __restrict__ K2, const u16* __restrict__ V2, const float* __restrict__ p2,
    const int* __restrict__ rs2, const int* __restrict__ cnt2, const int* __restrict__ col2, int nsrc2,
    float* __restrict__ Qio, int n_dst)
{
  int node = (blockIdx.x << 2) + (threadIdx.x >> 6);
  if(node >= n_dst) return;
  int lane = threadIdx.x & 63;
  int base = node*256 + (lane << 2);
  float4 qv = *(const float4*)(Qio + base);
  float q0=qv.x, q1=qv.y, q2=qv.z, q3=qv.w;
  float o0=0.f, o1=0.f, o2=0.f, o3=0.f;
  #pragma unroll
  for(int rel = 0; rel < NREL; rel++){
    const u16* Kr = rel ? K2 : K1;
    const u16* Vr = rel ? V2 : V1;
    const float* pr = rel ? p2 : p1;
    const int* rs = rel ? rs2 : rs1;
    const int* cn = rel ? cnt2 : cnt1;
    const int* cl = rel ? col2 : col1;
    const unsigned ns = (unsigned)(rel ? nsrc2 : nsrc1);
    float ps = pr[lane >> 3] * 0.17677669529663687f;   // p[h]/sqrt(32)
    float a0=0.f,a1=0.f,a2=0.f,a3=0.f,ss=0.f,mx=-1e30f;
    int r0 = rs[node], deg = cn[node];
    for(int i = 0; i < deg; i++){
      int s = cl[r0 + i];
      if((unsigned)s >= ns) continue;
      int kb = s*256 + (lane << 2);
      ushort4 kv = *(const ushort4*)(Kr + kb);
      float d = q0*b2f(kv.x) + q1*b2f(kv.y) + q2*b2f(kv.z) + q3*b2f(kv.w);
      d += __shfl_xor(d, 1);
      d += __shfl_xor(d, 2);
      d += __shfl_xor(d, 4);
      float l = d * ps;
      if(l > mx){
        float c = __expf(mx - l);
        ss *= c; a0 *= c; a1 *= c; a2 *= c; a3 *= c;
        mx = l;
      }
      float wgt = __expf(l - mx);
      ss += wgt;
      ushort4 vv = *(const ushort4*)(Vr + kb);
      a0 += wgt*b2f(vv.x); a1 += wgt*b2f(vv.y); a2 += wgt*b2f(vv.z); a3 += wgt*b2f(vv.w);
    }
    float inv = 1.f/(ss + 1e-16f);
    o0 += a0*inv; o1 += a1*inv; o2 += a2*inv; o3 += a3*inv;
  }
  const float c = 0.70710678118654752f;
  float4 ov;
  ov.x = 0.5f*o0*(1.f + erff(o0*c));
  ov.y = 0.5f*o1*(1.f + erff(o1*c));
  ov.z = 0.5f*o2*(1.f + erff(o2*c));
  ov.w = 0.5f*o3*(1.f + erff(o3*c));
  *(float4*)(Qio + base) = ov;
}

extern "C" void kernel_launch(void* const* d_in, const int* in_sizes, int n_in,
                              void* d_out, int out_size, void* d_ws, size_t ws_size,
                              hipStream_t stream)
{
  (void)n_in; (void)out_size; (void)ws_size;
  #define IN_F32(i) ((const float*)d_in[i])
  #define IN_I32(i) ((const int*)d_in[i])
  const int NG = in_sizes[0] / 128;
  const int ND = in_sizes[1] / 128;
  const int E  = in_sizes[34];

  char* p = (char*)d_ws;
  auto carve = [&](size_t bytes) -> void* {
    void* q = (void*)p; p += (bytes + 255) & ~(size_t)255; return q;
  };
  u16* XG   = (u16*)carve((size_t)NG*256*2);
  u16* XD   = (u16*)carve((size_t)ND*256*2);
  u16* bufA = (u16*)carve((size_t)NG*256*2);   // g2d K, then g2g K
  u16* bufB = (u16*)carve((size_t)NG*256*2);   // g2d V, then g2g V
  u16* KB   = (u16*)carve((size_t)ND*256*2);
  u16* VB   = (u16*)carve((size_t)ND*256*2);
  u16* WTinG = (u16*)carve(256*128*2);
  u16* WTinD = (u16*)carve(256*128*2);
  u16* WTqG  = (u16*)carve(256*256*2);
  u16* WTqD  = (u16*)carve(256*256*2);
  u16* WTaG  = (u16*)carve(256*256*2);
  u16* WTaD  = (u16*)carve(256*256*2);
  u16* WF[6]; for(int i=0;i<6;i++) WF[i] = (u16*)carve(256*256*2);
  float* FB[6]; for(int i=0;i<6;i++) FB[i] = (float*)carve(256*4);
  // CSR: zeroed zone (cnt x3, cur x3, tot) carved contiguously
  const int zn = 2*(ND + 2*NG) + 8;
  int* zone = (int*)carve((size_t)zn*4);
  int* cnt0 = zone;            // ND
  int* cnt1 = cnt0 + ND;       // NG
  int* cnt2 = cnt1 + NG;       // NG
  int* cur0 = cnt2 + NG;       // ND
  int* cur1 = cur0 + ND;       // NG
  int* cur2 = cur1 + NG;       // NG
  int* tot  = cur2 + NG;       // 8
  int* rs0 = (int*)carve((size_t)ND*4);
  int* rs1 = (int*)carve((size_t)NG*4);
  int* rs2 = (int*)carve((size_t)NG*4);
  int* col0 = (int*)carve((size_t)E*4);
  int* col1 = (int*)carve((size_t)E*4);
  int* col2 = (int*)carve((size_t)E*4);

  float* QGio = (float*)d_out;                     // fp32 [NG,256]
  float* QDio = (float*)d_out + (size_t)NG*256;    // fp32 [ND,256]

  // ---- prep (batched) ----
  {
    T6 a;
    const int wi[6] = {2,13,6,17,10,21};
    u16* wo[6] = {WTinG, WTinD, WTqG, WTqD, WTaG, WTaD};
    const int kk[6] = {128,128,256,256,256,256};
    for(int i=0;i<6;i++){ a.W[i]=IN_F32(wi[i]); a.O[i]=wo[i]; a.K[i]=kk[i]; }
    transpose6<<<dim3(256,6), 256, 0, stream>>>(a);
  }
  {
    F6 a; Fb6 b;
    const int wk[6] = {4,8,15,19,4,8};
    const int bk[6] = {5,9,16,20,5,9};
    const int am[6] = {24,25,27,28,30,31};
    for(int i=0;i<6;i++){
      a.Wk[i]=IN_F32(wk[i]); a.A[i]=IN_F32(am[i]); a.O[i]=WF[i];
      b.bk[i]=IN_F32(bk[i]); b.A[i]=IN_F32(am[i]); b.O[i]=FB[i];
    }
    foldw6<<<dim3(256,6), 256, 0, stream>>>(a);
    foldb6<<<6, 256, 0, stream>>>(b);
  }
  // ---- CSR (batched, all 3 relations up front) ----
  CSR3 c;
  c.src[0]=IN_I32(34); c.dst[0]=IN_I32(35); c.n[0]=ND;
  c.src[1]=IN_I32(36); c.dst[1]=IN_I32(37); c.n[1]=NG;
  c.src[2]=IN_I32(38); c.dst[2]=IN_I32(39); c.n[2]=NG;
  c.cnt[0]=cnt0; c.cnt[1]=cnt1; c.cnt[2]=cnt2;
  c.cur[0]=cur0; c.cur[1]=cur1; c.cur[2]=cur2;
  c.rs[0]=rs0; c.rs[1]=rs1; c.rs[2]=rs2;
  c.col[0]=col0; c.col[1]=col1; c.col[2]=col2;
  c.tot[0]=tot; c.tot[1]=tot+1; c.tot[2]=tot+2;
  const int eb = (E + 255) / 256;
  const int nb = (NG + 255) / 256;
  zero_k<<<(zn + 255) / 256, 256, 0, stream>>>(zone, zn);
  count3<<<dim3(eb,3), 256, 0, stream>>>(c, E);
  alloc3<<<dim3(nb,3), 256, 0, stream>>>(c);
  fill3<<<dim3(eb,3), 256, 0, stream>>>(c, E);

  // ---- GEMMs ----
  dim3 gG((NG + 127)/128, 2), gD((ND + 127)/128, 2);
  gemm128<1,0><<<gG, 256, 0, stream>>>(d_in[0], WTinG, IN_F32(3),  XG, NG, 128, nullptr, nullptr, nullptr);
  gemm128<1,0><<<gD, 256, 0, stream>>>(d_in[1], WTinD, IN_F32(14), XD, ND, 128, nullptr, nullptr, nullptr);

  // relation g2d (src=g, dst=d)
  gemm128<0,1><<<gD, 256, 0, stream>>>(XD, WTqD,  IN_F32(18), QDio, ND, 256, nullptr, nullptr, nullptr);
  gemm128<0,0><<<gG, 256, 0, stream>>>(XG, WF[0], FB[0], bufA, NG, 256, nullptr, nullptr, nullptr);
  gemm128<0,0><<<gG, 256, 0, stream>>>(XG, WF[1], FB[1], bufB, NG, 256, nullptr, nullptr, nullptr);
  message_gelu_k<1><<<(ND + 3) / 4, 256, 0, stream>>>(
      bufA, bufB, IN_F32(26), rs0, cnt0, col0, NG,
      nullptr, nullptr, nullptr, nullptr, nullptr, nullptr, 0,
      QDio, ND);

  // relations d2g + g2g (dst=g)
  gemm128<0,1><<<gG, 256, 0, stream>>>(XG, WTqG,  IN_F32(7), QGio, NG, 256, nullptr, nullptr, nullptr);
  gemm128<0,0><<<gD, 256, 0, stream>>>(XD, WF[2], FB[2], KB, ND, 256, nullptr, nullptr, nullptr);
  gemm128<0,0><<<gD, 256, 0, stream>>>(XD, WF[3], FB[3], VB, ND, 256, nullptr, nullptr, nullptr);
  gemm128<0,0><<<gG, 256, 0, stream>>>(XG, WF[4], FB[4], bufA, NG, 256, nullptr, nullptr, nullptr);
  gemm128<0,0><<<gG, 256, 0, stream>>>(XG, WF[5], FB[5], bufB, NG, 256, nullptr, nullptr, nullptr);
  message_gelu_k<2><<<(NG + 3) / 4, 256, 0, stream>>>(
      KB, VB, IN_F32(29), rs1, cnt1, col1, ND,
      bufA, bufB, IN_F32(32), rs2, cnt2, col2, NG,
      QGio, NG);

  // final epilogue GEMMs, in place over d_out (64x256 blocks own full rows)
  gemm128<1,2><<<dim3((NG + 63)/64, 1), 256, 0, stream>>>(
      QGio, WTaG, IN_F32(11), QGio, NG, 256, XG, IN_F32(12), IN_F32(33));
  gemm128<1,2><<<dim3((ND + 63)/64, 1), 256, 0, stream>>>(
      QDio, WTaD, IN_F32(22), QDio, ND, 256, XD, IN_F32(23), IN_F32(33));
  #undef IN_F32
  #undef IN_I32
}